// Round 5
// baseline (720.259 us; speedup 1.0000x reference)
//
#include <hip/hip_runtime.h>

// Problem constants
#define N_NODES 20000
#define N_ATTRS 5000
#define IN_F    512
#define OUT_F   128
#define KP      5120          // N_ATTRS padded: 10 chunks x 512
#define CHUNK   512           // attrs per chunk
#define NCH     10            // chunks (10*512 = 5120)
#define KLOC    16            // MFMA ksteps per chunk (512/32)
#define WH2_PAD 5376          // wh2 allocation incl. zeroed pad
#define LOG2E   1.4426950408889634f

typedef _Float16 f16x8 __attribute__((ext_vector_type(8)));
typedef float    f32x4 __attribute__((ext_vector_type(4)));
typedef int      i32x4 __attribute__((ext_vector_type(4)));   // clang vector: OK for nontemporal builtin

__device__ __forceinline__ float fast_exp2(float x) {
    return __builtin_amdgcn_exp2f(x);
}

// ---------------------------------------------------------------------------
// Kernel 1: Wa1 = W @ a[:128], Wa2 = W @ a[128:], both pre-scaled by log2(e);
// also repack W (fp32 [512x128] row-major) into f16 MFMA B-fragment order:
// idx = ((kb*8 + nb)*64 + lane)*8 + j  holds  W[kb*32 + (lane>>4)*8 + j][nb*16 + (lane&15)]
// ---------------------------------------------------------------------------
__global__ __launch_bounds__(256) void prep_kernel(
    const float* __restrict__ W, const float* __restrict__ a,
    float* __restrict__ Wa1, float* __restrict__ Wa2, _Float16* __restrict__ Wp) {
    int gt = blockIdx.x * blockDim.x + threadIdx.x;
    if (gt < IN_F) {
        int k = gt;
        float s1 = 0.f, s2 = 0.f;
        for (int f = 0; f < OUT_F; ++f) {
            float w = W[k * OUT_F + f];
            s1 += w * a[f];
            s2 += w * a[OUT_F + f];
        }
        Wa1[k] = s1 * LOG2E;
        Wa2[k] = s2 * LOG2E;
    }
    for (int idx = gt; idx < IN_F * OUT_F; idx += gridDim.x * blockDim.x) {
        int j    = idx & 7;
        int lane = (idx >> 3) & 63;
        int nb   = (idx >> 9) & 7;
        int kb   = idx >> 12;
        int k = kb * 32 + (lane >> 4) * 8 + j;
        int n = nb * 16 + (lane & 15);
        Wp[idx] = (_Float16)W[k * OUT_F + n];
    }
}

// ---------------------------------------------------------------------------
// Kernel 2: wh1[i] = node_emb[i] . Wa1 ; wh2[j] = attr_emb[j] . Wa2
// ---------------------------------------------------------------------------
__global__ __launch_bounds__(256) void wh_kernel(
    const float* __restrict__ node_emb, const float* __restrict__ attr_emb,
    const float* __restrict__ Wa1, const float* __restrict__ Wa2,
    float* __restrict__ wh1, float* __restrict__ wh2) {
    int wave = threadIdx.x >> 6, lane = threadIdx.x & 63;
    int r = blockIdx.x * 4 + wave;   // grid = 6250 -> r in [0, 25000)
    const float* src;
    const float* vec;
    float* dst;
    if (r < N_NODES) {
        src = node_emb + (size_t)r * IN_F; vec = Wa1; dst = wh1 + r;
    } else {
        int r2 = r - N_NODES;
        src = attr_emb + (size_t)r2 * IN_F; vec = Wa2; dst = wh2 + r2;
    }
    float4 ra = *reinterpret_cast<const float4*>(src + lane * 8);
    float4 rb = *reinterpret_cast<const float4*>(src + lane * 8 + 4);
    const float* vp = vec + lane * 8;
    float s = ra.x * vp[0] + ra.y * vp[1] + ra.z * vp[2] + ra.w * vp[3]
            + rb.x * vp[4] + rb.y * vp[5] + rb.z * vp[6] + rb.w * vp[7];
#pragma unroll
    for (int off = 1; off < 64; off <<= 1) s += __shfl_xor(s, off, 64);
    if (lane == 0) *dst = s;
}

// ---------------------------------------------------------------------------
// Kernel 2b: maxwh2 = max_j wh2[j]; zero wh2 pad region. single block.
// ---------------------------------------------------------------------------
__global__ __launch_bounds__(256) void max_kernel(
    float* __restrict__ wh2, float* __restrict__ maxp) {
    __shared__ float red[4];
    int t = threadIdx.x;
    float m = -1e30f;
    for (int j = t; j < N_ATTRS; j += 256) m = fmaxf(m, wh2[j]);
    for (int j = N_ATTRS + t; j < WH2_PAD; j += 256) wh2[j] = 0.f;
#pragma unroll
    for (int off = 1; off < 64; off <<= 1) m = fmaxf(m, __shfl_xor(m, off, 64));
    int wave = t >> 6, lane = t & 63;
    if (lane == 0) red[wave] = m;
    __syncthreads();
    if (t == 0) *maxp = fmaxf(fmaxf(red[0], red[1]), fmaxf(red[2], red[3]));
}

// ---------------------------------------------------------------------------
// Kernel 3: V = attr_emb @ W  [5120(pad) x 128] f16 in B-fragment order:
// Vp[kk*4096 + nb*512 + lane*8 + jj] = V[kk*32 + (lane>>4)*8 + jj][nb*16 + (lane&15)]
// ---------------------------------------------------------------------------
__global__ __launch_bounds__(256) void attr_h_kernel(
    const float* __restrict__ attr_emb, const _Float16* __restrict__ Wp,
    _Float16* __restrict__ Vp) {
    int wave = threadIdx.x >> 6, lane = threadIdx.x & 63;
    int m = lane & 15, quad = lane >> 4;
    int j0 = (blockIdx.x * 4 + wave) * 16;  // grid = 80 -> j0 in [0, 5120)
    int j = j0 + m;
    bool valid = j < N_ATTRS;
    f32x4 acc[8];
#pragma unroll
    for (int nb = 0; nb < 8; ++nb)
#pragma unroll
        for (int t = 0; t < 4; ++t) acc[nb][t] = 0.f;
    const float* arow = attr_emb + (size_t)j * IN_F;
    for (int kk = 0; kk < IN_F / 32; ++kk) {
        f16x8 afrag;
        if (valid) {
            float4 ra = *reinterpret_cast<const float4*>(arow + kk * 32 + quad * 8);
            float4 rb = *reinterpret_cast<const float4*>(arow + kk * 32 + quad * 8 + 4);
            afrag[0] = (_Float16)ra.x; afrag[1] = (_Float16)ra.y;
            afrag[2] = (_Float16)ra.z; afrag[3] = (_Float16)ra.w;
            afrag[4] = (_Float16)rb.x; afrag[5] = (_Float16)rb.y;
            afrag[6] = (_Float16)rb.z; afrag[7] = (_Float16)rb.w;
        } else {
#pragma unroll
            for (int t = 0; t < 8; ++t) afrag[t] = (_Float16)0.f;
        }
        const _Float16* wbase = Wp + (size_t)(kk * 8) * 64 * 8;
#pragma unroll
        for (int nb = 0; nb < 8; ++nb) {
            f16x8 bfrag;
            __builtin_memcpy(&bfrag, wbase + (nb * 64 + lane) * 8, 16);
            acc[nb] = __builtin_amdgcn_mfma_f32_16x16x32_f16(afrag, bfrag, acc[nb], 0, 0, 0);
        }
    }
#pragma unroll
    for (int nb = 0; nb < 8; ++nb) {
#pragma unroll
        for (int reg = 0; reg < 4; ++reg) {
            int jr = j0 + quad * 4 + reg;
            int n = nb * 16 + m;
            float v = (jr < N_ATTRS) ? acc[nb][reg] : 0.f;  // zero the K padding
            size_t idx = ((size_t)((jr >> 5) * 8 + nb) * 64 +
                          (((jr >> 3) & 3) * 16 + m)) * 8 + (jr & 7);
            Vp[idx] = (_Float16)v;
        }
    }
}

// ---------------------------------------------------------------------------
// Kernel 4 (main), restructured:
//  - block = 16 rows, 4 waves; wave w owns rows 4w..4w+3 for feat streaming
//  - feat read LINEARLY: per chunk (512 attrs), 8 independent nontemporal
//    dwordx4 wave-loads (1 KB contiguous each), issued right after the barrier
//    so they overlap the whole MFMA phase (no per-kstep consume dependency)
//  - p = f16(exp2(leaky(score) - Mi)) written to a swizzled LDS P buffer
//    (XOR swizzle: conflict-optimal for both ds_write_b64 and ds_read_b128)
//  - MFMA phase: each wave covers 4 of the chunk's 16 ksteps; A-frag from
//    LDS, B-frag from L2-resident Vp; 1 barrier per chunk (double-buffered P)
//  - epilogue reuses P buffer for cross-wave acc combine (LDS ~33 KB)
// ---------------------------------------------------------------------------
__global__ __launch_bounds__(256, 4) void attn_kernel(
    const int* __restrict__ feat, const float* __restrict__ wh1,
    const float* __restrict__ wh2, const float* __restrict__ maxwh2,
    const _Float16* __restrict__ Vp, float* __restrict__ out) {
    __shared__ unsigned int pbuf[2][KLOC * 256];   // 2 x 16 KB f16 P tiles (swizzled)
    __shared__ float rsums[16];

    int wave = threadIdx.x >> 6, lane = threadIdx.x & 63;
    int i0 = blockIdx.x * 16;          // grid = 1250
    int r0 = wave * 4;                 // local row base owned by this wave

    float mw2 = maxwh2[0];
    float w1[4], Mi[4];
#pragma unroll
    for (int rr = 0; rr < 4; ++rr) {
        float v = wh1[i0 + r0 + rr];
        w1[rr] = v;                    // scaled by log2(e)
        float em = v + mw2;
        Mi[rr] = fmaxf(em, 0.2f * em) - 12.f;   // f16 P lands in (0, 4096]
    }
    const int* fbase = feat + (size_t)(i0 + r0) * N_ATTRS;

    f32x4 acc[8];
#pragma unroll
    for (int nb = 0; nb < 8; ++nb)
#pragma unroll
        for (int t = 0; t < 4; ++t) acc[nb][t] = 0.f;
    float s[4] = {0.f, 0.f, 0.f, 0.f};

    // writer-side LDS constants (lane-fixed)
    int wK8  = lane >> 3;              // kstep offset within t-group (0..7)
    int wq   = (lane >> 1) & 3;        // quad
    int whh  = lane & 1;               // 8B half
    // reader-side
    int rq = lane >> 4;

    i32x4 fr[4][2];                    // staged feat: 4 rows x 2 t-groups
    // ---- prologue: issue loads for chunk 0 ----
#pragma unroll
    for (int rr = 0; rr < 4; ++rr)
#pragma unroll
        for (int t = 0; t < 2; ++t) {
            int off = t * 256 + 4 * lane;   // chunk 0: always in-bounds
            fr[rr][t] = __builtin_nontemporal_load(
                reinterpret_cast<const i32x4*>(fbase + (size_t)rr * N_ATTRS + off));
        }

    for (int c = 0; c < NCH; ++c) {
        char* pw = (char*)pbuf[c & 1];
        int cb = c * CHUNK;

        // ---- phase 1: compute p from staged feat, scatter into LDS ----
#pragma unroll
        for (int rr = 0; rr < 4; ++rr) {
            int m = r0 + rr;
#pragma unroll
            for (int t = 0; t < 2; ++t) {
                i32x4 f = fr[rr][t];
                int jg = cb + t * 256 + 4 * lane;           // global attr index
                float4 w2 = *reinterpret_cast<const float4*>(wh2 + jg);
                int   fi[4] = {f.x, f.y, f.z, f.w};
                float wv[4] = {w2.x, w2.y, w2.z, w2.w};
                union { _Float16 h[4]; uint2 u; } pk;
#pragma unroll
                for (int e = 0; e < 4; ++e) {
                    float ee = w1[rr] + wv[e];
                    float l = fmaxf(ee, 0.2f * ee);
                    float p = fast_exp2(l - Mi[rr]);
                    bool ok = (fi[e] > 0) && (jg + e < N_ATTRS);
                    p = ok ? p : 0.f;
                    _Float16 ph = (_Float16)p;
                    s[rr] += (float)ph;        // sum quantized p: weights sum to 1
                    pk.h[e] = ph;
                }
                int K = t * 8 + wK8;           // local kstep 0..15
                int S = (wq + 4 * (K & 1)) * 16;
                int addr = K * 1024 + (((m * 16 + wq * 256) + whh * 8) ^ S);
                *reinterpret_cast<uint2*>(pw + addr) = pk.u;
            }
        }

        __syncthreads();   // P(c) visible to all waves; cheap: no vmem in flight

        // ---- phase 2: issue next chunk's feat loads (fly across MFMA) ----
        {
            int ncb = (c + 1 < NCH) ? (c + 1) * CHUNK : 0;   // harmless reload on last
#pragma unroll
            for (int rr = 0; rr < 4; ++rr)
#pragma unroll
                for (int t = 0; t < 2; ++t) {
                    int off = ncb + t * 256 + 4 * lane;
                    off = min(off, N_ATTRS - 4);             // tail clamp (masked later)
                    fr[rr][t] = __builtin_nontemporal_load(
                        reinterpret_cast<const i32x4*>(fbase + (size_t)rr * N_ATTRS + off));
                }
        }

        // ---- phase 3: MFMA over this wave's 4 ksteps of chunk c ----
#pragma unroll
        for (int u = 0; u < 4; ++u) {
            int Kl = wave * 4 + u;
            int S = (rq + 4 * (Kl & 1)) * 16;
            f16x8 afrag;
            __builtin_memcpy(&afrag, pw + Kl * 1024 + ((lane * 16) ^ S), 16);
            const _Float16* vb = Vp + (size_t)(c * KLOC + Kl) * 4096;
#pragma unroll
            for (int nb = 0; nb < 8; ++nb) {
                f16x8 bfrag;
                __builtin_memcpy(&bfrag, vb + nb * 512 + lane * 8, 16);
                acc[nb] = __builtin_amdgcn_mfma_f32_16x16x32_f16(afrag, bfrag, acc[nb], 0, 0, 0);
            }
        }
        // NOTE: no barrier here — next iteration writes the OTHER P buffer,
        // and its phase-1->barrier ordering protects this buffer's readers.
    }

    // ---- row sums: each wave owns rows r0..r0+3 exclusively ----
#pragma unroll
    for (int rr = 0; rr < 4; ++rr) {
        float v = s[rr];
#pragma unroll
        for (int off = 1; off < 64; off <<= 1) v += __shfl_xor(v, off, 64);
        if (lane == 0) rsums[r0 + rr] = v;
    }

    // ---- cross-wave acc combine: reuse pbuf (stride 128, fits in pbuf[0]) ----
    float* accp = (float*)pbuf;        // 16*128*4 = 8192 B; epilogue runs once,
                                       // bank conflicts here are negligible
    int m16 = lane & 15, quad = lane >> 4;
#pragma unroll
    for (int w = 0; w < 4; ++w) {
        if (wave == w) {
            if (w == 0) {
#pragma unroll
                for (int nb = 0; nb < 8; ++nb)
#pragma unroll
                    for (int reg = 0; reg < 4; ++reg)
                        accp[(quad * 4 + reg) * 128 + nb * 16 + m16] = acc[nb][reg];
            } else {
#pragma unroll
                for (int nb = 0; nb < 8; ++nb)
#pragma unroll
                    for (int reg = 0; reg < 4; ++reg)
                        accp[(quad * 4 + reg) * 128 + nb * 16 + m16] += acc[nb][reg];
            }
        }
        __syncthreads();
    }

    // ---- normalize, ELU, store fp32 ----
    for (int o = threadIdx.x; o < 16 * 128; o += 256) {
        int lr = o >> 7, n = o & 127;
        float v = accp[lr * 128 + n];
        float rs = rsums[lr];
        rs = (rs > 0.f) ? rs : 1.f;
        float h = v / rs;
        float ov = (h > 0.f) ? h : (fast_exp2(h * LOG2E) - 1.f);
        out[(size_t)(i0 + lr) * OUT_F + n] = ov;
    }
}

// ---------------------------------------------------------------------------
extern "C" void kernel_launch(void* const* d_in, const int* in_sizes, int n_in,
                              void* d_out, int out_size, void* d_ws, size_t ws_size,
                              hipStream_t stream) {
    const float* node_emb = (const float*)d_in[0];  // fp32 [20000,512]
    const float* attr_emb = (const float*)d_in[1];  // fp32 [5000,512]
    const int*   feat     = (const int*)d_in[2];    // int32 [20000,5000]
    const float* W        = (const float*)d_in[3];  // fp32 [512,128]
    const float* a        = (const float*)d_in[4];  // fp32 [256,1]
    float*       out      = (float*)d_out;          // fp32 [20000,128]

    char* ws = (char*)d_ws;
    float*    Wa1 = (float*)(ws + 0);          // 512 f32
    float*    Wa2 = (float*)(ws + 4096);       // 512 f32
    float*    wh1 = (float*)(ws + 8192);       // 20000 f32 (ends 88192)
    float*    wh2 = (float*)(ws + 90112);      // 5376 f32 incl. zeroed pad (ends 111616)
    float*    mx  = (float*)(ws + 111616);     // 1 f32
    _Float16* Wp  = (_Float16*)(ws + 131072);  // 65536 f16 (ends 262144)
    _Float16* Vp  = (_Float16*)(ws + 262144);  // 5120*128 f16 (ends 1572864)

    prep_kernel<<<64, 256, 0, stream>>>(W, a, Wa1, Wa2, Wp);
    wh_kernel<<<6250, 256, 0, stream>>>(node_emb, attr_emb, Wa1, Wa2, wh1, wh2);
    max_kernel<<<1, 256, 0, stream>>>(wh2, mx);
    attr_h_kernel<<<80, 256, 0, stream>>>(attr_emb, Wp, Vp);
    attn_kernel<<<1250, 256, 0, stream>>>(feat, wh1, wh2, mx, Vp, out);
}